// Round 3
// baseline (755.587 us; speedup 1.0000x reference)
//
#include <hip/hip_runtime.h>
#include <math.h>
#include <stdint.h>

typedef _Float16 half8 __attribute__((ext_vector_type(8)));
typedef _Float16 half2v __attribute__((ext_vector_type(2)));
typedef float    f32x4 __attribute__((ext_vector_type(4)));
typedef unsigned int uint4v __attribute__((ext_vector_type(4)));

constexpr int Bc = 16, Nn = 2048, Dd = 256;
constexpr int QTI = 128;  // q rows per block (4 waves x 32)
constexpr int MC  = 64;   // m-chunk per iteration

__device__ _Float16 g_Wt[Dd * Dd];   // W^T, f16  (o-major: g_Wt[o][i])

__device__ __forceinline__ void gload16(const void* g, void* l) {
    __builtin_amdgcn_global_load_lds(
        (const __attribute__((address_space(1))) void*)g,
        (__attribute__((address_space(3))) void*)l, 16, 0, 0);
}

// ---------- transpose W (fp32 [i][o]) -> g_Wt (f16 [o][i]) ----------
__global__ void __launch_bounds__(256)
wt_transpose_kernel(const float* __restrict__ W) {
    __shared__ float ts[64][65];
    const int t = threadIdx.x;
    const int r0 = blockIdx.x * 64;   // i tile
    const int c0 = blockIdx.y * 64;   // o tile
    for (int idx = t; idx < 64 * 64; idx += 256) {
        const int i = idx >> 6, j = idx & 63;
        ts[i][j] = W[(r0 + i) * Dd + c0 + j];
    }
    __syncthreads();
    for (int idx = t; idx < 64 * 64; idx += 256) {
        const int c = idx >> 6, rl = idx & 63;
        g_Wt[(c0 + c) * Dd + r0 + rl] = (_Float16)ts[rl][c];
    }
}

// ---------- transpose nodes (fp32 [b][n][d]) -> vt (f16 [b][d][n]) ----------
__global__ void __launch_bounds__(256)
nodes_transpose_kernel(const float* __restrict__ nodes, _Float16* __restrict__ vt) {
    __shared__ float ts[64][65];
    const int t  = threadIdx.x;
    const int n0 = blockIdx.x * 64;
    const int d0 = blockIdx.y * 64;
    const int b  = blockIdx.z;
    const float* src = nodes + (size_t)b * Nn * Dd;
    _Float16*    dst = vt    + (size_t)b * Dd * Nn;
    for (int idx = t; idx < 64 * 64; idx += 256) {
        const int i = idx >> 6, j = idx & 63;
        ts[i][j] = src[(size_t)(n0 + i) * Dd + d0 + j];
    }
    __syncthreads();
    for (int idx = t; idx < 64 * 64; idx += 256) {
        const int d = idx >> 6, nl = idx & 63;
        dst[(size_t)(d0 + d) * Nn + n0 + nl] = (_Float16)ts[nl][d];
    }
}

// ---------- h = nodes @ W (MFMA f16, fp32 accum), W staged in LDS ----------
__global__ void __launch_bounds__(256, 2)
hgemm_kernel(const float* __restrict__ nodes, _Float16* __restrict__ h16) {
    __shared__ _Float16 Wt_s[128][264];
    const int t = threadIdx.x, w = t >> 6, lane = t & 63;
    const int quad = lane >> 4, l16 = lane & 15;
    const size_t row0 = (size_t)blockIdx.x * 64 + 16 * w;

    half8 aq[8];
    {
        const float* src = nodes + (row0 + l16) * Dd + quad * 8;
        #pragma unroll
        for (int kf = 0; kf < 8; ++kf) {
            const f32x4 a0 = *(const f32x4*)(src + kf * 32);
            const f32x4 a1 = *(const f32x4*)(src + kf * 32 + 4);
            half8 a;
            a[0] = (_Float16)a0[0]; a[1] = (_Float16)a0[1];
            a[2] = (_Float16)a0[2]; a[3] = (_Float16)a0[3];
            a[4] = (_Float16)a1[0]; a[5] = (_Float16)a1[1];
            a[6] = (_Float16)a1[2]; a[7] = (_Float16)a1[3];
            aq[kf] = a;
        }
    }
    f32x4 acc[16];
    #pragma unroll
    for (int ot = 0; ot < 16; ++ot) acc[ot] = (f32x4){0.f, 0.f, 0.f, 0.f};

    #pragma unroll
    for (int hh = 0; hh < 2; ++hh) {
        if (hh) __syncthreads();
        #pragma unroll
        for (int ii = 0; ii < 16; ++ii) {
            const int i = t + ii * 256;
            *(half8*)&Wt_s[i >> 5][(i & 31) * 8] =
                *(const half8*)&g_Wt[(size_t)(hh * 128 + (i >> 5)) * Dd + (i & 31) * 8];
        }
        __syncthreads();
        #pragma unroll
        for (int kf = 0; kf < 8; ++kf)
            #pragma unroll
            for (int ot = 0; ot < 8; ++ot) {
                const half8 bw = *(const half8*)&Wt_s[ot * 16 + l16][kf * 32 + quad * 8];
                acc[hh * 8 + ot] = __builtin_amdgcn_mfma_f32_16x16x32_f16(aq[kf], bw, acc[hh * 8 + ot], 0, 0, 0);
            }
    }
    #pragma unroll
    for (int idx = 0; idx < 16; ++idx) {
        const int hh = idx >> 3, ot = idx & 7;
        #pragma unroll
        for (int r = 0; r < 4; ++r)
            h16[(row0 + quad * 4 + r) * Dd + hh * 128 + ot * 16 + l16] = (_Float16)acc[idx][r];
    }
}

// ---------- fused flash-style GAT attention ----------
// Block = 128 q rows of one batch; 4 waves x 32 q (2 q-sets of 16).
// Per m-chunk: QK^T S^T strips for both q-sets sharing each hm A-frag;
// softmax lane-local (lane owns one q, 16 m) with exact defer-rescale;
// P^T packed f16, quad-redistributed via bpermute; PV shares each V A-frag
// across both q-sets. Staging: global_load_lds direct (16B), XOR-swizzled
// source + swizzled reads (conflict-free), double-buffered -> ONE
// __syncthreads per chunk (its vmcnt(0) drains loads issued a chunk ago).
__global__ void __launch_bounds__(256, 1)
gat_attn_kernel(const _Float16* __restrict__ h, const _Float16* __restrict__ vt,
                const float* __restrict__ adj, const float* __restrict__ bias,
                float* __restrict__ out) {
    __shared__ __align__(16) char lds_raw[131072];
    _Float16* hmA = (_Float16*)lds_raw;              // 32 KB: [64][256] linear
    _Float16* hmBuf = (_Float16*)(lds_raw + 32768);  // 32 KB
    _Float16* vA  = (_Float16*)(lds_raw + 65536);    // 32 KB: [256][64] linear
    _Float16* vBuf = (_Float16*)(lds_raw + 98304);   // 32 KB
    auto tw = (float (*)[16][69])lds_raw;            // epilogue alias (17.7 KB)

    const int t = threadIdx.x, w = t >> 6, lane = t & 63;
    const int quad = lane >> 4, l16 = lane & 15;
    const int b  = blockIdx.x & 15;        // batch -> XCD affinity
    const int q0 = (blockIdx.x >> 4) * QTI;

    const _Float16* hb = h   + (size_t)b * Nn * Dd;
    const _Float16* vb = vt  + (size_t)b * Dd * Nn;
    const float* abq0 = adj + ((size_t)b * Nn + (q0 + 32 * w + l16)) * Nn;
    const float* abq1 = abq0 + (size_t)16 * Nn;

    // ---- prologue: stage chunk 0 (hm + V) via gload_lds, adj chunk 0 ----
    #pragma unroll
    for (int ii = 0; ii < 8; ++ii) {
        const int i = t + ii * 256;
        const int mp = i >> 5, s = i & 31;
        gload16(hb + (size_t)mp * Dd + ((s ^ (mp & 7)) * 8), hmA + i * 8);
    }
    #pragma unroll
    for (int ii = 0; ii < 8; ++ii) {
        const int i = t + ii * 256;
        const int dp = i >> 3, s = i & 7;
        gload16(vb + (size_t)dp * Nn + ((s ^ (dp & 7)) * 8), vA + i * 8);
    }
    f32x4 adjA0[4], adjA1[4], adjB0[4], adjB1[4];
    #pragma unroll
    for (int mt = 0; mt < 4; ++mt) {
        adjA0[mt] = *(const f32x4*)(abq0 + mt * 16 + quad * 4);
        adjA1[mt] = *(const f32x4*)(abq1 + mt * 16 + quad * 4);
    }

    // persistent QK^T B-frags: q-set 0 -> q0+32w+l16, q-set 1 -> +16
    half8 bq0[8], bq1[8];
    {
        const _Float16* s0p = hb + (size_t)(q0 + 32 * w + l16) * Dd + quad * 8;
        #pragma unroll
        for (int kf = 0; kf < 8; ++kf) {
            bq0[kf] = *(const half8*)(s0p + kf * 32);
            bq1[kf] = *(const half8*)(s0p + 16 * Dd + kf * 32);
        }
    }

    f32x4 o0[16], o1[16];   // O^T frags: d = dt*16 + quad*4 + r, q = l16 (per set)
    #pragma unroll
    for (int dt = 0; dt < 16; ++dt) {
        o0[dt] = (f32x4){0.f, 0.f, 0.f, 0.f};
        o1[dt] = (f32x4){0.f, 0.f, 0.f, 0.f};
    }
    float m0 = -1e30f, l0 = 0.f, m1 = -1e30f, l1 = 0.f;

    const int s0 = ((lane >> 4) & 1) * 32 + l16;
    const int s1 = s0 + 16;
    const bool qlow = lane < 32;

    __syncthreads();   // chunk 0 in LDS (vmcnt(0) implied)

    // softmax for one q-set (exact defer-rescale: skip O-scale iff no new max)
    auto sm = [&](f32x4 (&stq)[4], const f32x4 (&aj)[4], float& mr, float& lr,
                  uint32_t (&pk)[4][2], f32x4 (&o)[16]) {
        float rm = -1e30f;
        #pragma unroll
        for (int mt = 0; mt < 4; ++mt)
            #pragma unroll
            for (int r = 0; r < 4; ++r) {
                float s = stq[mt][r];
                s = (s >= 0.f) ? s : 0.2f * s;
                s *= aj[mt][r];
                stq[mt][r] = s;
                rm = fmaxf(rm, s);
            }
        rm = fmaxf(rm, __shfl_xor(rm, 16));
        rm = fmaxf(rm, __shfl_xor(rm, 32));
        if (!__all(rm <= mr)) {
            const float mn    = fmaxf(mr, rm);
            const float alpha = __expf(mr - mn);
            mr = mn;
            lr *= alpha;
            #pragma unroll
            for (int dt = 0; dt < 16; ++dt) {
                o[dt][0] *= alpha; o[dt][1] *= alpha;
                o[dt][2] *= alpha; o[dt][3] *= alpha;
            }
        }
        float rs = 0.f;
        #pragma unroll
        for (int mt = 0; mt < 4; ++mt)
            #pragma unroll
            for (int r = 0; r < 4; ++r) {
                const float p = __expf(stq[mt][r] - mr);
                stq[mt][r] = p;
                rs += p;
            }
        rs += __shfl_xor(rs, 16);
        rs += __shfl_xor(rs, 32);
        lr += rs;
        #pragma unroll
        for (int mt = 0; mt < 4; ++mt) {
            half2v h01, h23;
            h01[0] = (_Float16)stq[mt][0]; h01[1] = (_Float16)stq[mt][1];
            h23[0] = (_Float16)stq[mt][2]; h23[1] = (_Float16)stq[mt][3];
            pk[mt][0] = __builtin_bit_cast(uint32_t, h01);
            pk[mt][1] = __builtin_bit_cast(uint32_t, h23);
        }
    };
    // P^T quad-redistribution -> PV B-frag (verified lane mapping)
    auto redist = [&](const uint32_t (&pk)[4][2], int ks) -> half8 {
        const int mA = 2 * ks, mB = 2 * ks + 1;
        uint4v bw_;
        const uint32_t a00 = (uint32_t)__shfl((int)pk[mA][0], s0);
        const uint32_t b00 = (uint32_t)__shfl((int)pk[mB][0], s0);
        const uint32_t a10 = (uint32_t)__shfl((int)pk[mA][1], s0);
        const uint32_t b10 = (uint32_t)__shfl((int)pk[mB][1], s0);
        const uint32_t a01 = (uint32_t)__shfl((int)pk[mA][0], s1);
        const uint32_t b01 = (uint32_t)__shfl((int)pk[mB][0], s1);
        const uint32_t a11 = (uint32_t)__shfl((int)pk[mA][1], s1);
        const uint32_t b11 = (uint32_t)__shfl((int)pk[mB][1], s1);
        bw_[0] = qlow ? a00 : b00;
        bw_[1] = qlow ? a10 : b10;
        bw_[2] = qlow ? a01 : b01;
        bw_[3] = qlow ? a11 : b11;
        return __builtin_bit_cast(half8, bw_);
    };

    auto chunk = [&](const _Float16* hmC, const _Float16* vC,
                     _Float16* hmN, _Float16* vN,
                     const f32x4 (&ac0)[4], const f32x4 (&ac1)[4],
                     f32x4 (&an0)[4], f32x4 (&an1)[4], int mb) {
        const int mb2 = mb + MC;
        if (mb2 < Nn) {   // prefetch chunk mb+MC: gload_lds + adj regs
            #pragma unroll
            for (int ii = 0; ii < 8; ++ii) {
                const int i = t + ii * 256;
                const int mp = i >> 5, s = i & 31;
                gload16(hb + (size_t)(mb2 + mp) * Dd + ((s ^ (mp & 7)) * 8), hmN + i * 8);
            }
            #pragma unroll
            for (int ii = 0; ii < 8; ++ii) {
                const int i = t + ii * 256;
                const int dp = i >> 3, s = i & 7;
                gload16(vb + (size_t)dp * Nn + mb2 + ((s ^ (dp & 7)) * 8), vN + i * 8);
            }
            #pragma unroll
            for (int mt = 0; mt < 4; ++mt) {
                an0[mt] = *(const f32x4*)(abq0 + mb2 + mt * 16 + quad * 4);
                an1[mt] = *(const f32x4*)(abq1 + mb2 + mt * 16 + quad * 4);
            }
        }

        // ---- QK^T: both q-sets share each hm A-frag ----
        f32x4 st0[4], st1[4];
        #pragma unroll
        for (int mt = 0; mt < 4; ++mt) {
            st0[mt] = (f32x4){0.f, 0.f, 0.f, 0.f};
            st1[mt] = (f32x4){0.f, 0.f, 0.f, 0.f};
        }
        #pragma unroll
        for (int kf = 0; kf < 8; ++kf)
            #pragma unroll
            for (int mt = 0; mt < 4; ++mt) {
                const int m  = mt * 16 + l16;
                const int pg = (kf * 4 + quad) ^ (m & 7);
                const half8 am = *(const half8*)(hmC + m * 256 + pg * 8);
                st0[mt] = __builtin_amdgcn_mfma_f32_16x16x32_f16(am, bq0[kf], st0[mt], 0, 0, 0);
                st1[mt] = __builtin_amdgcn_mfma_f32_16x16x32_f16(am, bq1[kf], st1[mt], 0, 0, 0);
            }

        // ---- softmax + pack per q-set ----
        uint32_t pk0[4][2], pk1[4][2];
        sm(st0, ac0, m0, l0, pk0, o0);
        sm(st1, ac1, m1, l1, pk1, o1);

        // ---- PV: both q-sets share each V A-frag ----
        #pragma unroll
        for (int ks = 0; ks < 2; ++ks) {
            const half8 bp0 = redist(pk0, ks);
            const half8 bp1 = redist(pk1, ks);
            #pragma unroll
            for (int dt = 0; dt < 16; ++dt) {
                const int d  = dt * 16 + l16;
                const int pg = (ks * 4 + quad) ^ (d & 7);
                const half8 va = *(const half8*)(vC + d * 64 + pg * 8);
                o0[dt] = __builtin_amdgcn_mfma_f32_16x16x32_f16(va, bp0, o0[dt], 0, 0, 0);
                o1[dt] = __builtin_amdgcn_mfma_f32_16x16x32_f16(va, bp1, o1[dt], 0, 0, 0);
            }
        }
        __syncthreads();   // next chunk visible; all waves done with current bufs
    };

    for (int mb = 0; mb < Nn; mb += 2 * MC) {
        chunk(hmA, vA, hmBuf, vBuf, adjA0, adjA1, adjB0, adjB1, mb);
        chunk(hmBuf, vBuf, hmA, vA, adjB0, adjB1, adjA0, adjA1, mb + MC);
    }

    // ---- epilogue: scale by 1/L, per-wave LDS transpose, coalesced store ----
    auto epi = [&](f32x4 (&o)[16], float lr, int qrow) {
        const float invl = 1.f / lr;
        #pragma unroll
        for (int dt = 0; dt < 16; ++dt) {
            o[dt][0] *= invl; o[dt][1] *= invl;
            o[dt][2] *= invl; o[dt][3] *= invl;
        }
        float* T = &tw[w][0][0];
        const int rr = lane >> 2, cg = lane & 3;
        float* orow = out + ((size_t)b * Nn + qrow + rr) * Dd;
        #pragma unroll
        for (int dc = 0; dc < 4; ++dc) {
            #pragma unroll
            for (int k4 = 0; k4 < 4; ++k4)
                #pragma unroll
                for (int r = 0; r < 4; ++r)
                    T[l16 * 69 + k4 * 16 + quad * 4 + r] = o[dc * 4 + k4][r];
            asm volatile("s_waitcnt lgkmcnt(0)" ::: "memory");
            #pragma unroll
            for (int c = 0; c < 4; ++c) {
                f32x4 v;
                #pragma unroll
                for (int e = 0; e < 4; ++e) v[e] = T[rr * 69 + cg * 16 + 4 * c + e];
                const int d = dc * 64 + cg * 16 + 4 * c;
                const f32x4 bs = *(const f32x4*)(bias + d);
                v[0] += bs[0]; v[1] += bs[1]; v[2] += bs[2]; v[3] += bs[3];
                *(f32x4*)(orow + d) = v;
            }
            asm volatile("s_waitcnt lgkmcnt(0)" ::: "memory");  // WAR vs next dc
        }
    };
    epi(o0, l0, q0 + 32 * w);
    epi(o1, l1, q0 + 32 * w + 16);
}

extern "C" void kernel_launch(void* const* d_in, const int* in_sizes, int n_in,
                              void* d_out, int out_size, void* d_ws, size_t ws_size,
                              hipStream_t stream) {
    const float* nodes = (const float*)d_in[0];  // [16,2048,256]
    const float* adj   = (const float*)d_in[1];  // [16,2048,2048]
    const float* W     = (const float*)d_in[2];  // [256,256]
    const float* bias  = (const float*)d_in[3];  // [256]
    float* out = (float*)d_out;

    _Float16* h16 = (_Float16*)d_ws;                       // 16.78 MB
    _Float16* vtp = h16 + (size_t)Bc * Nn * Dd;            // 16.78 MB (total 33.55 MB)

    hipLaunchKernelGGL(wt_transpose_kernel, dim3(4, 4), dim3(256), 0, stream, W);
    hipLaunchKernelGGL(nodes_transpose_kernel, dim3(32, 4, 16), dim3(256), 0, stream, nodes, vtp);
    hipLaunchKernelGGL(hgemm_kernel, dim3(512), dim3(256), 0, stream, nodes, h16);
    hipLaunchKernelGGL(gat_attn_kernel, dim3(256), dim3(256), 0, stream, h16, vtp, adj, bias, out);
}

// Round 5
// 471.368 us; speedup vs baseline: 1.6030x; 1.6030x over previous
//
#include <hip/hip_runtime.h>
#include <math.h>
#include <stdint.h>

typedef _Float16 half8 __attribute__((ext_vector_type(8)));
typedef _Float16 half2v __attribute__((ext_vector_type(2)));
typedef float    f32x4 __attribute__((ext_vector_type(4)));
typedef unsigned int uint4v __attribute__((ext_vector_type(4)));

constexpr int Bc = 16, Nn = 2048, Dd = 256;
constexpr int QTI = 64;   // q rows per block (4 waves x 16)
constexpr int MC  = 32;   // m-chunk per iteration (16KB hm + 16KB V per buffer)

__device__ _Float16 g_Wt[Dd * Dd];   // W^T, f16  (o-major: g_Wt[o][i])

__device__ __forceinline__ void gload16(const void* g, void* l) {
    __builtin_amdgcn_global_load_lds(
        (const __attribute__((address_space(1))) void*)g,
        (__attribute__((address_space(3))) void*)l, 16, 0, 0);
}

// ---------- transpose W (fp32 [i][o]) -> g_Wt (f16 [o][i]) ----------
__global__ void __launch_bounds__(256)
wt_transpose_kernel(const float* __restrict__ W) {
    __shared__ float ts[64][65];
    const int t = threadIdx.x;
    const int r0 = blockIdx.x * 64;   // i tile
    const int c0 = blockIdx.y * 64;   // o tile
    for (int idx = t; idx < 64 * 64; idx += 256) {
        const int i = idx >> 6, j = idx & 63;
        ts[i][j] = W[(r0 + i) * Dd + c0 + j];
    }
    __syncthreads();
    for (int idx = t; idx < 64 * 64; idx += 256) {
        const int c = idx >> 6, rl = idx & 63;
        g_Wt[(c0 + c) * Dd + r0 + rl] = (_Float16)ts[rl][c];
    }
}

// ---------- fused: h = nodes @ W (MFMA) + vt = nodes^T (f16) ----------
// 512 blocks x 256 thr; wave owns 16 rows (full K=256 in f16 regs).
// Phase 1: W^T staged in LDS (two 128-o halves), 128 MFMA/wave -> h16.
// Phase 2: reuse LDS as swizzled [256 d][64 n] f16 tile built from the SAME
// registers -> vt written in 128B row segments (vs old kernel's extra 134MB
// nodes pass + 128B-granule writes).
// Swizzle: column granule cg = (n>>3) ^ ((d>>3)&7). Writes: 2 lanes/bank
// (free); reads: each 8-lane phase hits 8 distinct granule slots (free).
__global__ void __launch_bounds__(256, 2)
hgemm_vt_kernel(const float* __restrict__ nodes, _Float16* __restrict__ h16,
                _Float16* __restrict__ vt) {
    __shared__ __align__(16) char lds_raw[67584];
    _Float16 (*Wt_s)[264] = (_Float16 (*)[264])lds_raw;   // 128 x 264
    _Float16* ts = (_Float16*)lds_raw;                    // alias: [256][64]

    const int t = threadIdx.x, w = t >> 6, lane = t & 63;
    const int quad = lane >> 4, l16 = lane & 15;
    const size_t row0 = (size_t)blockIdx.x * 64 + 16 * w;

    half8 aq[8];
    {
        const float* src = nodes + (row0 + l16) * Dd + quad * 8;
        #pragma unroll
        for (int kf = 0; kf < 8; ++kf) {
            const f32x4 a0 = *(const f32x4*)(src + kf * 32);
            const f32x4 a1 = *(const f32x4*)(src + kf * 32 + 4);
            half8 a;
            a[0] = (_Float16)a0[0]; a[1] = (_Float16)a0[1];
            a[2] = (_Float16)a0[2]; a[3] = (_Float16)a0[3];
            a[4] = (_Float16)a1[0]; a[5] = (_Float16)a1[1];
            a[6] = (_Float16)a1[2]; a[7] = (_Float16)a1[3];
            aq[kf] = a;
        }
    }
    f32x4 acc[16];
    #pragma unroll
    for (int ot = 0; ot < 16; ++ot) acc[ot] = (f32x4){0.f, 0.f, 0.f, 0.f};

    #pragma unroll
    for (int hh = 0; hh < 2; ++hh) {
        if (hh) __syncthreads();
        #pragma unroll
        for (int ii = 0; ii < 16; ++ii) {
            const int i = t + ii * 256;
            *(half8*)&Wt_s[i >> 5][(i & 31) * 8] =
                *(const half8*)&g_Wt[(size_t)(hh * 128 + (i >> 5)) * Dd + (i & 31) * 8];
        }
        __syncthreads();
        #pragma unroll
        for (int kf = 0; kf < 8; ++kf)
            #pragma unroll
            for (int ot = 0; ot < 8; ++ot) {
                const half8 bw = *(const half8*)&Wt_s[ot * 16 + l16][kf * 32 + quad * 8];
                acc[hh * 8 + ot] = __builtin_amdgcn_mfma_f32_16x16x32_f16(aq[kf], bw, acc[hh * 8 + ot], 0, 0, 0);
            }
    }
    #pragma unroll
    for (int idx = 0; idx < 16; ++idx) {
        const int hh = idx >> 3, ot = idx & 7;
        #pragma unroll
        for (int r = 0; r < 4; ++r)
            h16[(row0 + quad * 4 + r) * Dd + hh * 128 + ot * 16 + l16] = (_Float16)acc[idx][r];
    }

    // ---- phase 2: swizzled LDS transpose from aq regs -> vt ----
    __syncthreads();   // all Wt_s reads done before alias
    const int n_local = 16 * w + l16;
    #pragma unroll
    for (int kf = 0; kf < 8; ++kf)
        #pragma unroll
        for (int j = 0; j < 8; ++j) {
            const int d = kf * 32 + quad * 8 + j;
            const int col = (((n_local >> 3) ^ ((d >> 3) & 7)) * 8) + (n_local & 7);
            ts[d * 64 + col] = aq[kf][j];
        }
    __syncthreads();
    const int b  = (int)(((size_t)blockIdx.x * 64) >> 11);
    const int nb = (int)(((size_t)blockIdx.x * 64) & 2047);
    _Float16* vdst = vt + (size_t)b * Dd * Nn;
    #pragma unroll
    for (int ii = 0; ii < 8; ++ii) {
        const int i = t + ii * 256;
        const int d = i >> 3, g = i & 7;
        const int pg = g ^ ((d >> 3) & 7);
        const half8 v = *(const half8*)(ts + d * 64 + pg * 8);
        *(half8*)(vdst + (size_t)d * Nn + nb + g * 8) = v;
    }
}

// ---------- fused flash-style GAT attention ----------
// Round-2 skeleton (QTI=64, 512 blocks, 2 blocks/CU, 8 waves/CU) with:
//   * MC=32 chunks, double-buffered global_load_lds staging (no ds_writes,
//     no staging VGPRs); ONE __syncthreads per chunk (its implicit vmcnt(0)
//     drains loads issued a full chunk earlier).
//   * Bank-exact XOR swizzles: hm granule pg = s ^ (m&7); V stored as 128B
//     row-pairs, pg = ((d&1)*4+quad) ^ ((d>>1)&7) -- all 8 phases of each
//     ds_read_b128 hit 32 distinct banks.
//   * S^T lane math, in-register P with bpermute redistribution, exact
//     defer-rescale (all verified in rounds 1-3).
__global__ void __launch_bounds__(256, 2)
gat_attn_kernel(const _Float16* __restrict__ h, const _Float16* __restrict__ vt,
                const float* __restrict__ adj, const float* __restrict__ bias,
                float* __restrict__ out) {
    __shared__ __align__(16) char lds_raw[65536];
    _Float16* hmA = (_Float16*)lds_raw;               // [32][256] linear, swz granules
    _Float16* hmB = (_Float16*)(lds_raw + 16384);
    _Float16* vA  = (_Float16*)(lds_raw + 32768);     // [128 rowpairs][8 granules]
    _Float16* vB  = (_Float16*)(lds_raw + 49152);
    auto tw = (float (*)[16][69])lds_raw;             // epilogue alias (17.7 KB)

    const int t = threadIdx.x, w = t >> 6, lane = t & 63;
    const int quad = lane >> 4, l16 = lane & 15;
    const int b  = blockIdx.x & 15;        // batch -> XCD affinity
    const int q0 = (blockIdx.x >> 4) * QTI;

    const _Float16* hb = h   + (size_t)b * Nn * Dd;
    const _Float16* vb = vt  + (size_t)b * Dd * Nn;
    const float*   abq = adj + ((size_t)b * Nn + (q0 + 16 * w + l16)) * Nn;  // lane's q row

    auto STAGE = [&](int mb, _Float16* hmX, _Float16* vX) {
        #pragma unroll
        for (int ii = 0; ii < 4; ++ii) {
            const int i = t + ii * 256;
            const int mp = i >> 5, s = i & 31;
            gload16(hb + (size_t)(mb + mp) * Dd + ((s ^ (mp & 7)) * 8), hmX + i * 8);
        }
        #pragma unroll
        for (int ii = 0; ii < 4; ++ii) {
            const int i = t + ii * 256;
            const int r = i >> 3, pg = i & 7;
            const int g = pg ^ (r & 7);
            gload16(vb + (size_t)(2 * r + (g >> 2)) * Nn + mb + (g & 3) * 8, vX + i * 8);
        }
    };

    // ---- prologue: stage chunk 0, adj chunk 0, persistent q-frags ----
    STAGE(0, hmA, vA);
    f32x4 adjA[2], adjB[2];
    #pragma unroll
    for (int mt = 0; mt < 2; ++mt)
        adjA[mt] = *(const f32x4*)(abq + mt * 16 + quad * 4);

    half8 bq[8];
    {
        const _Float16* s = hb + (size_t)(q0 + 16 * w + l16) * Dd + quad * 8;
        #pragma unroll
        for (int kf = 0; kf < 8; ++kf) bq[kf] = *(const half8*)(s + kf * 32);
    }

    f32x4 ot_[16];   // O^T frags: d = dt*16 + quad*4 + r, q = l16
    #pragma unroll
    for (int dt = 0; dt < 16; ++dt) ot_[dt] = (f32x4){0.f, 0.f, 0.f, 0.f};
    float m_run = -1e30f, l_run = 0.f;

    const int s0 = ((lane >> 4) & 1) * 32 + l16;
    const int s1 = s0 + 16;
    const bool qlow = lane < 32;

    __syncthreads();   // chunk 0 visible (implicit vmcnt(0))

    auto CHUNK = [&](int mb, const _Float16* hmC, const _Float16* vC,
                     _Float16* hmN, _Float16* vN,
                     const f32x4 (&ac)[2], f32x4 (&an)[2]) {
        const int mb2 = mb + MC;
        if (mb2 < Nn) {   // prefetch next chunk (drained by end-of-chunk barrier)
            STAGE(mb2, hmN, vN);
            #pragma unroll
            for (int mt = 0; mt < 2; ++mt)
                an[mt] = *(const f32x4*)(abq + mb2 + mt * 16 + quad * 4);
        }

        // ---- QK^T: S^T strip 32(m) x 16(q), A-frags from LDS (swz) ----
        f32x4 st[2];
        st[0] = (f32x4){0.f, 0.f, 0.f, 0.f};
        st[1] = (f32x4){0.f, 0.f, 0.f, 0.f};
        __builtin_amdgcn_s_setprio(1);
        #pragma unroll
        for (int kf = 0; kf < 8; ++kf)
            #pragma unroll
            for (int mt = 0; mt < 2; ++mt) {
                const int m  = mt * 16 + l16;
                const int pg = (kf * 4 + quad) ^ (m & 7);
                const half8 am = *(const half8*)(hmC + m * 256 + pg * 8);
                st[mt] = __builtin_amdgcn_mfma_f32_16x16x32_f16(am, bq[kf], st[mt], 0, 0, 0);
            }
        __builtin_amdgcn_s_setprio(0);

        // ---- leaky * adj + online softmax (lane owns q=l16, 8 m-values) ----
        float rm = -1e30f;
        #pragma unroll
        for (int mt = 0; mt < 2; ++mt)
            #pragma unroll
            for (int r = 0; r < 4; ++r) {
                float s = st[mt][r];
                s = (s >= 0.f) ? s : 0.2f * s;
                s *= ac[mt][r];
                st[mt][r] = s;
                rm = fmaxf(rm, s);
            }
        rm = fmaxf(rm, __shfl_xor(rm, 16));
        rm = fmaxf(rm, __shfl_xor(rm, 32));
        if (!__all(rm <= m_run)) {     // exact defer-rescale
            const float mn    = fmaxf(m_run, rm);
            const float alpha = __expf(m_run - mn);
            m_run = mn;
            l_run *= alpha;
            #pragma unroll
            for (int dt = 0; dt < 16; ++dt) {
                ot_[dt][0] *= alpha; ot_[dt][1] *= alpha;
                ot_[dt][2] *= alpha; ot_[dt][3] *= alpha;
            }
        }
        float rs = 0.f;
        #pragma unroll
        for (int mt = 0; mt < 2; ++mt)
            #pragma unroll
            for (int r = 0; r < 4; ++r) {
                const float p = __expf(st[mt][r] - m_run);
                st[mt][r] = p;
                rs += p;
            }
        rs += __shfl_xor(rs, 16);
        rs += __shfl_xor(rs, 32);
        l_run += rs;

        // ---- pack P^T (RNE) and redistribute across quads (ks=0 only) ----
        uint32_t pk[2][2];
        #pragma unroll
        for (int mt = 0; mt < 2; ++mt) {
            half2v h01, h23;
            h01[0] = (_Float16)st[mt][0]; h01[1] = (_Float16)st[mt][1];
            h23[0] = (_Float16)st[mt][2]; h23[1] = (_Float16)st[mt][3];
            pk[mt][0] = __builtin_bit_cast(uint32_t, h01);
            pk[mt][1] = __builtin_bit_cast(uint32_t, h23);
        }
        uint4v bw_;
        {
            const uint32_t a00 = (uint32_t)__shfl((int)pk[0][0], s0);
            const uint32_t b00 = (uint32_t)__shfl((int)pk[1][0], s0);
            const uint32_t a10 = (uint32_t)__shfl((int)pk[0][1], s0);
            const uint32_t b10 = (uint32_t)__shfl((int)pk[1][1], s0);
            const uint32_t a01 = (uint32_t)__shfl((int)pk[0][0], s1);
            const uint32_t b01 = (uint32_t)__shfl((int)pk[1][0], s1);
            const uint32_t a11 = (uint32_t)__shfl((int)pk[0][1], s1);
            const uint32_t b11 = (uint32_t)__shfl((int)pk[1][1], s1);
            bw_[0] = qlow ? a00 : b00;
            bw_[1] = qlow ? a10 : b10;
            bw_[2] = qlow ? a01 : b01;
            bw_[3] = qlow ? a11 : b11;
        }
        const half8 bp = __builtin_bit_cast(half8, bw_);

        // ---- PV: A-frags from LDS V (row-pair swz); O^T += V^T . P^T ----
        __builtin_amdgcn_s_setprio(1);
        #pragma unroll
        for (int dt = 0; dt < 16; ++dt) {
            const int d  = dt * 16 + l16;
            const int rp = d >> 1;
            const int gq = ((d & 1) * 4 + quad) ^ (rp & 7);
            const half8 va = *(const half8*)(vC + rp * 64 + gq * 8);
            ot_[dt] = __builtin_amdgcn_mfma_f32_16x16x32_f16(va, bp, ot_[dt], 0, 0, 0);
        }
        __builtin_amdgcn_s_setprio(0);

        __syncthreads();   // next chunk visible; all waves done with cur bufs
    };

    for (int mb = 0; mb < Nn; mb += 2 * MC) {
        CHUNK(mb,      hmA, vA, hmB, vB, adjA, adjB);
        CHUNK(mb + MC, hmB, vB, hmA, vA, adjB, adjA);
    }

    // ---- epilogue: scale by 1/L, per-wave LDS transpose, coalesced store ----
    __syncthreads();   // before aliasing tw over hm buffers
    const float invl = 1.f / l_run;
    #pragma unroll
    for (int dt = 0; dt < 16; ++dt) {
        ot_[dt][0] *= invl; ot_[dt][1] *= invl;
        ot_[dt][2] *= invl; ot_[dt][3] *= invl;
    }
    float* T = &tw[w][0][0];
    const int rr = lane >> 2, cg = lane & 3;
    float* orow = out + ((size_t)b * Nn + q0 + 16 * w + rr) * Dd;
    #pragma unroll
    for (int dc = 0; dc < 4; ++dc) {
        #pragma unroll
        for (int k4 = 0; k4 < 4; ++k4)
            #pragma unroll
            for (int r = 0; r < 4; ++r)
                T[l16 * 69 + k4 * 16 + quad * 4 + r] = ot_[dc * 4 + k4][r];
        asm volatile("s_waitcnt lgkmcnt(0)" ::: "memory");
        #pragma unroll
        for (int c = 0; c < 4; ++c) {
            f32x4 v;
            #pragma unroll
            for (int e = 0; e < 4; ++e) v[e] = T[rr * 69 + cg * 16 + 4 * c + e];
            const int d = dc * 64 + cg * 16 + 4 * c;
            const f32x4 bs = *(const f32x4*)(bias + d);
            v[0] += bs[0]; v[1] += bs[1]; v[2] += bs[2]; v[3] += bs[3];
            *(f32x4*)(orow + d) = v;
        }
        asm volatile("s_waitcnt lgkmcnt(0)" ::: "memory");  // WAR vs next dc
    }
}

extern "C" void kernel_launch(void* const* d_in, const int* in_sizes, int n_in,
                              void* d_out, int out_size, void* d_ws, size_t ws_size,
                              hipStream_t stream) {
    const float* nodes = (const float*)d_in[0];  // [16,2048,256]
    const float* adj   = (const float*)d_in[1];  // [16,2048,2048]
    const float* W     = (const float*)d_in[2];  // [256,256]
    const float* bias  = (const float*)d_in[3];  // [256]
    float* out = (float*)d_out;

    _Float16* h16 = (_Float16*)d_ws;                       // 16.78 MB
    _Float16* vtp = h16 + (size_t)Bc * Nn * Dd;            // 16.78 MB (total 33.55 MB)

    hipLaunchKernelGGL(wt_transpose_kernel, dim3(4, 4), dim3(256), 0, stream, W);
    hipLaunchKernelGGL(hgemm_vt_kernel, dim3(512), dim3(256), 0, stream, nodes, h16, vtp);
    hipLaunchKernelGGL(gat_attn_kernel, dim3(512), dim3(256), 0, stream, h16, vtp, adj, bias, out);
}